// Round 9
// baseline (258.007 us; speedup 1.0000x reference)
//
#include <hip/hip_runtime.h>
#include <hip/hip_bf16.h>

#define E_TOT 500000
#define N_NODES 100000

typedef __attribute__((ext_vector_type(16))) float f32x16;
typedef __attribute__((ext_vector_type(8))) short short8;
typedef __attribute__((ext_vector_type(4))) float f32x4;

__device__ __forceinline__ unsigned short f2bf(float f) {
  union { float f; unsigned u; } x; x.f = f;
  unsigned r = x.u + 0x7fffu + ((x.u >> 16) & 1u);
  return (unsigned short)(r >> 16);
}

__device__ __forceinline__ float bf2f(unsigned short s) {
  union { unsigned u; float f; } x; x.u = ((unsigned)s) << 16;
  return x.f;
}

__device__ __forceinline__ short cvt1(float f) {
  __hip_bfloat16 h = __float2bfloat16(f);  // v_cvt RNE; compiler fuses pairs
  union { __hip_bfloat16 h; short s; } u; u.h = h;
  return u.s;
}

__device__ __forceinline__ void gl_lds16(const void* g, void* l) {
  __builtin_amdgcn_global_load_lds(
      (const __attribute__((address_space(1))) void*)g,
      (__attribute__((address_space(3))) void*)l, 16, 0, 0);
}

// w1 (f32 [256][512]) -> w1r2 bf16 [half][kseg=0..31][n=0..255][j=0..7]
__global__ void k_repack_w1h(const float* __restrict__ w1,
                             unsigned short* __restrict__ w1r2) {
  int o = blockIdx.x * 256 + threadIdx.x;  // 131072 total
  int half = o >> 16;
  int kb = (o >> 11) & 31;
  int n = (o >> 3) & 255;
  int j = o & 7;
  w1r2[o] = f2bf(w1[n * 512 + half * 256 + kb * 8 + j]);
}

// U'[n] = zsrc[n] @ W1s^T + b1 (half 0) ; V[n] = zdst[n] @ W1d^T (half 1)
// v9: persistent 1 block/CU; whole B panel in LDS (once); per-wave autonomous
// units (32 rows x 64 cols), A prefetch pipeline, zero main-loop barriers.
__global__ __launch_bounds__(1024, 4) void k_node_gemm(
    const float* __restrict__ zsrc, const float* __restrict__ zdst,
    const unsigned short* __restrict__ w1r2, const float* __restrict__ b1,
    unsigned short* __restrict__ Uo, unsigned short* __restrict__ Vo) {
  __shared__ __align__(16) unsigned short Bl[65536];  // 128 KB: full half-panel

  const int b = blockIdx.x;   // 256 blocks, 1 per CU (LDS-forced)
  const int half = b >> 7;    // 128 blocks per half
  const int bh = b & 127;
  const float* Z = half ? zdst : zsrc;
  unsigned short* O = half ? Vo : Uo;

  const unsigned tid = threadIdx.x;
  const unsigned l = tid & 63u;
  const unsigned wv = tid >> 6;  // 0..15
  const unsigned l31 = l & 31u;
  const unsigned hi = l >> 5;

  // ---- stage this half's full B panel into LDS, once ----
  {
    const unsigned short* src = w1r2 + (unsigned)half * 65536u;
#pragma unroll
    for (int q = 0; q < 8; ++q) {
      unsigned off = ((unsigned)q * 1024u + tid) * 8u;  // shorts, 16B/lane
      gl_lds16(src + off, Bl + off);
    }
  }
  __syncthreads();  // only barrier; drains staging

  const unsigned slot = (unsigned)bh * 16u + wv;  // 0..2047 within half
  // units per half: 3125 strips x 4 col-units = 12500
  for (unsigned u = slot; u < 12500u; u += 2048u) {
    const unsigned strip = u >> 2;
    const unsigned cu_ = u & 3u;
    const unsigned row = strip * 32u + l31;
    const float* ap = Z + (unsigned long)row * 256u + hi * 8u;

    float bia0 = 0.f, bia1 = 0.f;
    if (!half) {
      bia0 = b1[cu_ * 64u + l31];
      bia1 = b1[cu_ * 64u + 32u + l31];
    }

    f32x16 acc0 = {0.f, 0.f, 0.f, 0.f, 0.f, 0.f, 0.f, 0.f,
                   0.f, 0.f, 0.f, 0.f, 0.f, 0.f, 0.f, 0.f};
    f32x16 acc1 = acc0;

    // 4-slot A prefetch pipeline (static indices via full unroll)
    f32x4 sl[4][2];
#pragma unroll
    for (int s = 0; s < 4; ++s) {
      sl[s][0] = ((const f32x4*)(ap + s * 16))[0];
      sl[s][1] = ((const f32x4*)(ap + s * 16))[1];
    }

#pragma unroll
    for (int kb = 0; kb < 16; ++kb) {
      const int sI = kb & 3;
      short8 af;
      af[0] = cvt1(sl[sI][0].x); af[1] = cvt1(sl[sI][0].y);
      af[2] = cvt1(sl[sI][0].z); af[3] = cvt1(sl[sI][0].w);
      af[4] = cvt1(sl[sI][1].x); af[5] = cvt1(sl[sI][1].y);
      af[6] = cvt1(sl[sI][1].z); af[7] = cvt1(sl[sI][1].w);
      if (kb < 12) {  // refill slot with kb+4's granule
        sl[sI][0] = ((const f32x4*)(ap + (kb + 4) * 16))[0];
        sl[sI][1] = ((const f32x4*)(ap + (kb + 4) * 16))[1];
      }
      const unsigned ksg = (unsigned)kb * 2u + hi;
      short8 bf0 = *(const short8*)&Bl[(ksg * 256u + cu_ * 64u + l31) * 8u];
      short8 bf1 = *(const short8*)&Bl[(ksg * 256u + cu_ * 64u + 32u + l31) * 8u];
      acc0 = __builtin_amdgcn_mfma_f32_32x32x16_bf16(af, bf0, acc0, 0, 0, 0);
      acc1 = __builtin_amdgcn_mfma_f32_32x32x16_bf16(af, bf1, acc1, 0, 0, 0);
    }

    // stores: unit covers exactly one 128B line per row; ct pair completes
    // the line in adjacent instructions (L2 merges; no RMW amplification).
    unsigned short* ob = O + (unsigned long)(strip * 32u) * 256u + cu_ * 64u;
#pragma unroll
    for (int r = 0; r < 16; ++r) {
      unsigned rr = (unsigned)((r & 3) + 8 * (r >> 2)) + 4u * hi;
      unsigned short* po = ob + (unsigned long)rr * 256u;
      po[l31] = f2bf(acc0[r] + bia0);
      po[32u + l31] = f2bf(acc1[r] + bia1);
    }
  }
}

// per edge: out = sigmoid( w2 . relu(U'[row] + V[col]) + b2 )
// 3-stage pipeline: idx(e+2) || rows(e+1) || compute(e)
#define EK_ITER 16
__global__ __launch_bounds__(256, 6) void k_edge(
    const unsigned short* __restrict__ U, const unsigned short* __restrict__ V,
    const int* __restrict__ eli, const float* __restrict__ w2,
    const float* __restrict__ b2, float* __restrict__ out) {
  const int tid = threadIdx.x;
  const int g = tid >> 4;
  const int j = tid & 15;
  float w2v[16];
#pragma unroll
  for (int q = 0; q < 8; ++q) {
    w2v[q] = w2[8 * j + q];
    w2v[8 + q] = w2[128 + 8 * j + q];
  }
  const float b2v = b2[0];
  const long base = (long)blockIdx.x * (16 * EK_ITER) + g;

#define CLAMP_E(k) \
  (((base + 16 * (k)) < E_TOT) ? (base + 16 * (k)) : (long)(E_TOT - 1))

  long eP = CLAMP_E(0);
  int rA = eli[eP], cA = eli[E_TOT + eP];
  long eQ = CLAMP_E(1);
  int rB = eli[eQ], cB = eli[E_TOT + eQ];
  short8 uA0 = *(const short8*)(U + (long)rA * 256 + 8 * j);
  short8 uA1 = *(const short8*)(U + (long)rA * 256 + 128 + 8 * j);
  short8 vA0 = *(const short8*)(V + (long)cA * 256 + 8 * j);
  short8 vA1 = *(const short8*)(V + (long)cA * 256 + 128 + 8 * j);
  short8 uB0, uB1, vB0, vB1;

#pragma unroll
  for (int it2 = 0; it2 < EK_ITER / 2; ++it2) {
    {
      long eN = CLAMP_E(2 * it2 + 2);
      int rN = eli[eN], cN = eli[E_TOT + eN];
      uB0 = *(const short8*)(U + (long)rB * 256 + 8 * j);
      uB1 = *(const short8*)(U + (long)rB * 256 + 128 + 8 * j);
      vB0 = *(const short8*)(V + (long)cB * 256 + 8 * j);
      vB1 = *(const short8*)(V + (long)cB * 256 + 128 + 8 * j);
      rB = rN; cB = cN;
      float p = 0.f;
#pragma unroll
      for (int q = 0; q < 8; ++q) {
        float a0 = bf2f((unsigned short)uA0[q]) + bf2f((unsigned short)vA0[q]);
        float a1 = bf2f((unsigned short)uA1[q]) + bf2f((unsigned short)vA1[q]);
        p = fmaf(fmaxf(a0, 0.f), w2v[q], p);
        p = fmaf(fmaxf(a1, 0.f), w2v[8 + q], p);
      }
      p += __shfl_xor(p, 1);
      p += __shfl_xor(p, 2);
      p += __shfl_xor(p, 4);
      p += __shfl_xor(p, 8);
      long e = base + 16 * (2 * it2);
      if (j == 0 && e < E_TOT) out[e] = 1.f / (1.f + __expf(-(p + b2v)));
    }
    {
      long eN = CLAMP_E(2 * it2 + 3);
      int rN = eli[eN], cN = eli[E_TOT + eN];
      uA0 = *(const short8*)(U + (long)rB * 256 + 8 * j);
      uA1 = *(const short8*)(U + (long)rB * 256 + 128 + 8 * j);
      vA0 = *(const short8*)(V + (long)cB * 256 + 8 * j);
      vA1 = *(const short8*)(V + (long)cB * 256 + 128 + 8 * j);
      rB = rN; cB = cN;
      float p = 0.f;
#pragma unroll
      for (int q = 0; q < 8; ++q) {
        float a0 = bf2f((unsigned short)uB0[q]) + bf2f((unsigned short)vB0[q]);
        float a1 = bf2f((unsigned short)uB1[q]) + bf2f((unsigned short)vB1[q]);
        p = fmaf(fmaxf(a0, 0.f), w2v[q], p);
        p = fmaf(fmaxf(a1, 0.f), w2v[8 + q], p);
      }
      p += __shfl_xor(p, 1);
      p += __shfl_xor(p, 2);
      p += __shfl_xor(p, 4);
      p += __shfl_xor(p, 8);
      long e = base + 16 * (2 * it2 + 1);
      if (j == 0 && e < E_TOT) out[e] = 1.f / (1.f + __expf(-(p + b2v)));
    }
  }
#undef CLAMP_E
}

extern "C" void kernel_launch(void* const* d_in, const int* in_sizes, int n_in,
                              void* d_out, int out_size, void* d_ws,
                              size_t ws_size, hipStream_t stream) {
  const float* zsrc = (const float*)d_in[0];
  const float* zdst = (const float*)d_in[1];
  const int* eli = (const int*)d_in[2];
  const float* w1 = (const float*)d_in[3];
  const float* b1 = (const float*)d_in[4];
  const float* w2 = (const float*)d_in[5];
  const float* b2 = (const float*)d_in[6];
  float* out = (float*)d_out;

  const size_t uv_bytes = (size_t)N_NODES * 256 * 2;  // 51.2 MB each
  unsigned short* U = (unsigned short*)d_ws;
  unsigned short* V = (unsigned short*)((char*)d_ws + uv_bytes);
  unsigned short* w1r2 = (unsigned short*)((char*)d_ws + 2 * uv_bytes);

  k_repack_w1h<<<512, 256, 0, stream>>>(w1, w1r2);
  k_node_gemm<<<256, 1024, 0, stream>>>(zsrc, zdst, w1r2, b1, U, V);
  int nbe = (E_TOT + 16 * EK_ITER - 1) / (16 * EK_ITER);
  k_edge<<<nbe, 256, 0, stream>>>(U, V, eli, w2, b2, out);
}

// Round 10
// 162.046 us; speedup vs baseline: 1.5922x; 1.5922x over previous
//
#include <hip/hip_runtime.h>

#define E_TOT 500000
#define N_NODES 100000
#define NSTRIPS 6250          // 3125 per half, 32 rows each
#define HALF_STRIPS 3125
#define NGB 768               // node-gemm grid (3 blocks/CU)

typedef __attribute__((ext_vector_type(16))) float f32x16;
typedef __attribute__((ext_vector_type(8))) short short8;
typedef __attribute__((ext_vector_type(4))) float f32x4;

__device__ __forceinline__ unsigned short f2bf(float f) {
  union { float f; unsigned u; } x; x.f = f;
  unsigned r = x.u + 0x7fffu + ((x.u >> 16) & 1u);
  return (unsigned short)(r >> 16);
}

__device__ __forceinline__ float bf2f(unsigned short s) {
  union { unsigned u; float f; } x; x.u = ((unsigned)s) << 16;
  return x.f;
}

// w1 (f32 [256][512]) -> w1r2 bf16 [half][kseg=0..31][n=0..255][j=0..7]
__global__ void k_repack_w1h(const float* __restrict__ w1,
                             unsigned short* __restrict__ w1r2) {
  int o = blockIdx.x * 256 + threadIdx.x;  // 131072 total
  int half = o >> 16;
  int kb = (o >> 11) & 31;
  int n = (o >> 3) & 255;
  int j = o & 7;
  w1r2[o] = f2bf(w1[n * 512 + half * 256 + kb * 8 + j]);
}

// U'[n] = zsrc[n] @ W1s^T + b1 (half 0) ; V[n] = zdst[n] @ W1d^T (half 1)
// v10: strip-persistent blocks (32 rows x 256 cols per strip), B via rolling
// register prefetch from L2 (no B LDS), A async-split staged to 16KB LDS,
// C via 8KB LDS tile -> full 128B-line stores. Small LDS -> 3 blocks/CU.
__global__ __launch_bounds__(256, 3) void k_node_gemm(
    const float* __restrict__ zsrc, const float* __restrict__ zdst,
    const unsigned short* __restrict__ w1r2, const float* __restrict__ b1,
    unsigned short* __restrict__ Uo, unsigned short* __restrict__ Vo) {
  __shared__ __align__(16) unsigned short A_lds[16 * 2 * 32 * 8];  // 16 KB
  __shared__ __align__(16) unsigned short Ct[16][264];             // 8448 B

  const unsigned tid = threadIdx.x;
  const unsigned l = tid & 63u;
  const unsigned w = tid >> 6;   // wave 0..3 -> cols w*64..w*64+63
  const unsigned l31 = l & 31u;
  const unsigned hi = l >> 5;
  const unsigned arow = tid & 31u;  // A-staging: row within strip
  const unsigned akq = tid >> 5;    // A-staging: 32-float k-granule (0..7)

  f32x4 ap[8];  // pending A: 32 floats = k range [akq*32, akq*32+32)

#define LOAD_A(ss)                                                   \
  {                                                                  \
    int h_ = (ss) >= HALF_STRIPS;                                    \
    const float* Z_ = h_ ? zdst : zsrc;                              \
    long row_ = (long)((ss) - h_ * HALF_STRIPS) * 32 + arow;         \
    const f32x4* p_ = (const f32x4*)(Z_ + row_ * 256 + akq * 32u);   \
    _Pragma("unroll") for (int g = 0; g < 8; ++g) ap[g] = p_[g];     \
  }

#define WRITE_A()                                                      \
  {                                                                    \
    _Pragma("unroll") for (int g = 0; g < 4; ++g) {                    \
      short8 sa;                                                       \
      sa[0] = (short)f2bf(ap[2 * g].x); sa[1] = (short)f2bf(ap[2 * g].y); \
      sa[2] = (short)f2bf(ap[2 * g].z); sa[3] = (short)f2bf(ap[2 * g].w); \
      sa[4] = (short)f2bf(ap[2 * g + 1].x); sa[5] = (short)f2bf(ap[2 * g + 1].y); \
      sa[6] = (short)f2bf(ap[2 * g + 1].z); sa[7] = (short)f2bf(ap[2 * g + 1].w); \
      unsigned ks_ = 2u * akq + (unsigned)(g >> 1);                    \
      unsigned h_ = (unsigned)(g & 1);                                 \
      *(short8*)&A_lds[((ks_ * 2u + h_) * 32u + arow) * 8u] = sa;      \
    }                                                                  \
  }

  int s = blockIdx.x;
  LOAD_A(s);
  WRITE_A();
  __syncthreads();

  for (; s < NSTRIPS; s += NGB) {
    const int half = s >= HALF_STRIPS;
    const long srow = (long)(s - half * HALF_STRIPS) * 32;
    unsigned short* O = half ? Vo : Uo;
    const unsigned short* bb = w1r2 + (unsigned)half * 65536u;

    float bi0 = 0.f, bi1 = 0.f;
    if (!half) {
      bi0 = b1[w * 64u + l31];
      bi1 = b1[w * 64u + 32u + l31];
    }

    // issue A(next strip) NOW -> lands during compute (async split)
    {
      int sn = s + NGB;
      if (sn >= NSTRIPS) sn = s;
      LOAD_A(sn);
    }

    // B rolling prefetch (4 deep x 2 frags), straight from L2
    short8 bq[4][2];
#pragma unroll
    for (int k = 0; k < 4; ++k) {
      const unsigned short* p =
          bb + (((unsigned)k * 2u + hi) * 256u + w * 64u + l31) * 8u;
      bq[k][0] = *(const short8*)p;
      bq[k][1] = *(const short8*)(p + 256);  // +32 cols
    }

    f32x16 acc0 = {0.f, 0.f, 0.f, 0.f, 0.f, 0.f, 0.f, 0.f,
                   0.f, 0.f, 0.f, 0.f, 0.f, 0.f, 0.f, 0.f};
    f32x16 acc1 = acc0;

#pragma unroll
    for (int k = 0; k < 16; ++k) {
      short8 af = *(const short8*)&A_lds[(((unsigned)k * 2u + hi) * 32u + l31) * 8u];
      short8 b0 = bq[k & 3][0];
      short8 b1f = bq[k & 3][1];
      if (k < 12) {
        const unsigned short* p =
            bb + (((unsigned)(k + 4) * 2u + hi) * 256u + w * 64u + l31) * 8u;
        bq[k & 3][0] = *(const short8*)p;
        bq[k & 3][1] = *(const short8*)(p + 256);
      }
      acc0 = __builtin_amdgcn_mfma_f32_32x32x16_bf16(af, b0, acc0, 0, 0, 0);
      acc1 = __builtin_amdgcn_mfma_f32_32x32x16_bf16(af, b1f, acc1, 0, 0, 0);
    }

    __syncthreads();  // compute done (A_lds free); A(next) long since landed
    WRITE_A();        // stage A(next) for the following iteration

    // rows 0..15 (r<8): write C tile
#pragma unroll
    for (int r = 0; r < 8; ++r) {
      unsigned row32 = (unsigned)((r & 3) + 8 * (r >> 2)) + 4u * hi;  // 0..15
      Ct[row32][w * 64u + l31] = f2bf(acc0[r] + bi0);
      Ct[row32][w * 64u + 32u + l31] = f2bf(acc1[r] + bi1);
    }
    __syncthreads();
#pragma unroll
    for (int p = 0; p < 2; ++p) {
      unsigned row = tid >> 4;
      unsigned seg = (tid & 15u) + (unsigned)p * 16u;
      short8 vv = *(const short8*)&Ct[row][seg * 8u];
      *(short8*)(O + (srow + row) * 256 + seg * 8u) = vv;
    }
    __syncthreads();

    // rows 16..31 (r>=8)
#pragma unroll
    for (int r = 8; r < 16; ++r) {
      unsigned row32 = (unsigned)((r & 3) + 8 * (r >> 2)) + 4u * hi;  // 16..31
      Ct[row32 - 16u][w * 64u + l31] = f2bf(acc0[r] + bi0);
      Ct[row32 - 16u][w * 64u + 32u + l31] = f2bf(acc1[r] + bi1);
    }
    __syncthreads();
#pragma unroll
    for (int p = 0; p < 2; ++p) {
      unsigned row = tid >> 4;
      unsigned seg = (tid & 15u) + (unsigned)p * 16u;
      short8 vv = *(const short8*)&Ct[row][seg * 8u];
      *(short8*)(O + (srow + 16 + row) * 256 + seg * 8u) = vv;
    }
    // no barrier needed: next iter's first barrier orders these tile reads
    // against the next tile writes; A_lds already synced above.
  }
#undef LOAD_A
#undef WRITE_A
}

// per edge: out = sigmoid( w2 . relu(U'[row] + V[col]) + b2 )
// 3-stage pipeline: idx(e+2) || rows(e+1) || compute(e)
#define EK_ITER 16
__global__ __launch_bounds__(256, 6) void k_edge(
    const unsigned short* __restrict__ U, const unsigned short* __restrict__ V,
    const int* __restrict__ eli, const float* __restrict__ w2,
    const float* __restrict__ b2, float* __restrict__ out) {
  const int tid = threadIdx.x;
  const int g = tid >> 4;
  const int j = tid & 15;
  float w2v[16];
#pragma unroll
  for (int q = 0; q < 8; ++q) {
    w2v[q] = w2[8 * j + q];
    w2v[8 + q] = w2[128 + 8 * j + q];
  }
  const float b2v = b2[0];
  const long base = (long)blockIdx.x * (16 * EK_ITER) + g;

#define CLAMP_E(k) \
  (((base + 16 * (k)) < E_TOT) ? (base + 16 * (k)) : (long)(E_TOT - 1))

  long eP = CLAMP_E(0);
  int rA = eli[eP], cA = eli[E_TOT + eP];
  long eQ = CLAMP_E(1);
  int rB = eli[eQ], cB = eli[E_TOT + eQ];
  short8 uA0 = *(const short8*)(U + (long)rA * 256 + 8 * j);
  short8 uA1 = *(const short8*)(U + (long)rA * 256 + 128 + 8 * j);
  short8 vA0 = *(const short8*)(V + (long)cA * 256 + 8 * j);
  short8 vA1 = *(const short8*)(V + (long)cA * 256 + 128 + 8 * j);
  short8 uB0, uB1, vB0, vB1;

#pragma unroll
  for (int it2 = 0; it2 < EK_ITER / 2; ++it2) {
    {
      long eN = CLAMP_E(2 * it2 + 2);
      int rN = eli[eN], cN = eli[E_TOT + eN];
      uB0 = *(const short8*)(U + (long)rB * 256 + 8 * j);
      uB1 = *(const short8*)(U + (long)rB * 256 + 128 + 8 * j);
      vB0 = *(const short8*)(V + (long)cB * 256 + 8 * j);
      vB1 = *(const short8*)(V + (long)cB * 256 + 128 + 8 * j);
      rB = rN; cB = cN;
      float p = 0.f;
#pragma unroll
      for (int q = 0; q < 8; ++q) {
        float a0 = bf2f((unsigned short)uA0[q]) + bf2f((unsigned short)vA0[q]);
        float a1 = bf2f((unsigned short)uA1[q]) + bf2f((unsigned short)vA1[q]);
        p = fmaf(fmaxf(a0, 0.f), w2v[q], p);
        p = fmaf(fmaxf(a1, 0.f), w2v[8 + q], p);
      }
      p += __shfl_xor(p, 1);
      p += __shfl_xor(p, 2);
      p += __shfl_xor(p, 4);
      p += __shfl_xor(p, 8);
      long e = base + 16 * (2 * it2);
      if (j == 0 && e < E_TOT) out[e] = 1.f / (1.f + __expf(-(p + b2v)));
    }
    {
      long eN = CLAMP_E(2 * it2 + 3);
      int rN = eli[eN], cN = eli[E_TOT + eN];
      uA0 = *(const short8*)(U + (long)rB * 256 + 8 * j);
      uA1 = *(const short8*)(U + (long)rB * 256 + 128 + 8 * j);
      vA0 = *(const short8*)(V + (long)cB * 256 + 8 * j);
      vA1 = *(const short8*)(V + (long)cB * 256 + 128 + 8 * j);
      rB = rN; cB = cN;
      float p = 0.f;
#pragma unroll
      for (int q = 0; q < 8; ++q) {
        float a0 = bf2f((unsigned short)uB0[q]) + bf2f((unsigned short)vB0[q]);
        float a1 = bf2f((unsigned short)uB1[q]) + bf2f((unsigned short)vB1[q]);
        p = fmaf(fmaxf(a0, 0.f), w2v[q], p);
        p = fmaf(fmaxf(a1, 0.f), w2v[8 + q], p);
      }
      p += __shfl_xor(p, 1);
      p += __shfl_xor(p, 2);
      p += __shfl_xor(p, 4);
      p += __shfl_xor(p, 8);
      long e = base + 16 * (2 * it2 + 1);
      if (j == 0 && e < E_TOT) out[e] = 1.f / (1.f + __expf(-(p + b2v)));
    }
  }
#undef CLAMP_E
}

extern "C" void kernel_launch(void* const* d_in, const int* in_sizes, int n_in,
                              void* d_out, int out_size, void* d_ws,
                              size_t ws_size, hipStream_t stream) {
  const float* zsrc = (const float*)d_in[0];
  const float* zdst = (const float*)d_in[1];
  const int* eli = (const int*)d_in[2];
  const float* w1 = (const float*)d_in[3];
  const float* b1 = (const float*)d_in[4];
  const float* w2 = (const float*)d_in[5];
  const float* b2 = (const float*)d_in[6];
  float* out = (float*)d_out;

  const size_t uv_bytes = (size_t)N_NODES * 256 * 2;  // 51.2 MB each
  unsigned short* U = (unsigned short*)d_ws;
  unsigned short* V = (unsigned short*)((char*)d_ws + uv_bytes);
  unsigned short* w1r2 = (unsigned short*)((char*)d_ws + 2 * uv_bytes);

  k_repack_w1h<<<512, 256, 0, stream>>>(w1, w1r2);
  k_node_gemm<<<NGB, 256, 0, stream>>>(zsrc, zdst, w1r2, b1, U, V);
  int nbe = (E_TOT + 16 * EK_ITER - 1) / (16 * EK_ITER);
  k_edge<<<nbe, 256, 0, stream>>>(U, V, eli, w2, b2, out);
}

// Round 11
// 155.225 us; speedup vs baseline: 1.6621x; 1.0439x over previous
//
#include <hip/hip_runtime.h>

#define E_TOT 500000
#define N_NODES 100000
#define NUNITS_H 3125   // 32-row units per half (exact: 3125*32 = 100000)

typedef __attribute__((ext_vector_type(16))) float f32x16;
typedef __attribute__((ext_vector_type(8))) short short8;
typedef __attribute__((ext_vector_type(4))) float f32x4;

__device__ __forceinline__ unsigned short f2bf(float f) {
  union { float f; unsigned u; } x; x.f = f;
  unsigned r = x.u + 0x7fffu + ((x.u >> 16) & 1u);
  return (unsigned short)(r >> 16);
}

__device__ __forceinline__ float bf2f(unsigned short s) {
  union { unsigned u; float f; } x; x.u = ((unsigned)s) << 16;
  return x.f;
}

__device__ __forceinline__ void gl_lds16(const void* g, void* l) {
  __builtin_amdgcn_global_load_lds(
      (const __attribute__((address_space(1))) void*)g,
      (__attribute__((address_space(3))) void*)l, 16, 0, 0);
}

// w1 (f32 [256][512]) -> w1r2 bf16 [half][kseg=0..31][n=0..255][j=0..7]
__global__ void k_repack_w1h(const float* __restrict__ w1,
                             unsigned short* __restrict__ w1r2) {
  int o = blockIdx.x * 256 + threadIdx.x;  // 131072 total
  int half = o >> 16;
  int kb = (o >> 11) & 31;
  int n = (o >> 3) & 255;
  int j = o & 7;
  w1r2[o] = f2bf(w1[n * 512 + half * 256 + kb * 8 + j]);
}

// U'[n] = zsrc[n] @ W1s^T + b1 (half 0) ; V[n] = zdst[n] @ W1d^T (half 1)
// v11: 1 block/CU, whole B half-panel resident in LDS; per 32-row unit:
// A(next) burst to regs at top (sched_barrier-pinned), all-LDS MFMA loop,
// A->LDS + C->Ct tile after barrier, full-line stores. 2 barriers/unit.
__global__ __launch_bounds__(512, 1) void k_node_gemm(
    const float* __restrict__ zsrc, const float* __restrict__ zdst,
    const unsigned short* __restrict__ w1r2, const float* __restrict__ b1,
    unsigned short* __restrict__ Uo, unsigned short* __restrict__ Vo) {
  __shared__ __align__(16) unsigned short Bp[65536];  // 128 KB: W1 half-panel
  __shared__ __align__(16) unsigned short Ap[8192];   // 16 KB: 32-row A unit
  __shared__ __align__(16) unsigned short Ct[8192];   // 16 KB: C tile

  const int half = blockIdx.x >> 7;   // 128 blocks per half
  const int bh = blockIdx.x & 127;
  const float* Z = half ? zdst : zsrc;
  unsigned short* O = half ? Vo : Uo;

  const unsigned tid = threadIdx.x;
  const unsigned l = tid & 63u;
  const unsigned wv = tid >> 6;   // wave 0..7 -> cols wv*32..wv*32+31
  const unsigned l31 = l & 31u;
  const unsigned hi = l >> 5;
  const unsigned arow = tid & 31u;  // A-staging row
  const unsigned ak2 = tid >> 5;    // A-staging 16-float granule (0..15)

  // ---- stage this half's full B panel into LDS, once ----
  {
    const unsigned short* src = w1r2 + (unsigned)half * 65536u;
#pragma unroll
    for (int q = 0; q < 16; ++q) {
      unsigned off = ((unsigned)q * 512u + tid) * 8u;
      gl_lds16(src + off, Bp + off);
    }
  }

  const float bi = half ? 0.f : b1[wv * 32u + l31];

  f32x4 ap[4];  // pending A: 16 floats = k [ak2*16, ak2*16+16)
#define LOAD_A(uu)                                                        \
  {                                                                       \
    const f32x4* p_ =                                                     \
        (const f32x4*)(Z + ((long)(uu)*32 + arow) * 256 + ak2 * 16u);     \
    ap[0] = p_[0]; ap[1] = p_[1]; ap[2] = p_[2]; ap[3] = p_[3];           \
  }
#define WRITE_A()                                                         \
  {                                                                       \
    _Pragma("unroll") for (int g = 0; g < 2; ++g) {                       \
      short8 sa;                                                          \
      sa[0] = (short)f2bf(ap[2*g].x);   sa[1] = (short)f2bf(ap[2*g].y);   \
      sa[2] = (short)f2bf(ap[2*g].z);   sa[3] = (short)f2bf(ap[2*g].w);   \
      sa[4] = (short)f2bf(ap[2*g+1].x); sa[5] = (short)f2bf(ap[2*g+1].y); \
      sa[6] = (short)f2bf(ap[2*g+1].z); sa[7] = (short)f2bf(ap[2*g+1].w); \
      *(short8*)&Ap[((2u*ak2 + (unsigned)g)*32u + arow)*8u] = sa;         \
    }                                                                     \
  }

  int u = bh;
  LOAD_A(u);
  WRITE_A();
  __syncthreads();  // drains B staging + A(u0) writes

  for (; u < NUNITS_H; u += 128) {
    int un = u + 128;
    if (un >= NUNITS_H) un = u;  // tail: reload same unit (harmless)
    LOAD_A(un);                  // in flight during compute + store phases
    __builtin_amdgcn_sched_barrier(0);  // pin: do not sink these loads

    f32x16 acc = {0.f, 0.f, 0.f, 0.f, 0.f, 0.f, 0.f, 0.f,
                  0.f, 0.f, 0.f, 0.f, 0.f, 0.f, 0.f, 0.f};
#pragma unroll
    for (int kk = 0; kk < 16; ++kk) {
      unsigned ks = 2u * (unsigned)kk + hi;
      short8 af = *(const short8*)&Ap[(ks * 32u + l31) * 8u];
      short8 bf = *(const short8*)&Bp[(ks * 256u + wv * 32u + l31) * 8u];
      acc = __builtin_amdgcn_mfma_f32_32x32x16_bf16(af, bf, acc, 0, 0, 0);
    }
    __syncthreads();  // compute done: Ap free, Ct free

    WRITE_A();        // A(un) -> Ap for next iteration
#pragma unroll
    for (int r = 0; r < 16; ++r) {
      unsigned row32 = (unsigned)((r & 3) + 8 * (r >> 2)) + 4u * hi;
      Ct[row32 * 256u + wv * 32u + l31] = f2bf(acc[r] + bi);
    }
    __syncthreads();  // Ct visible (and WRITE_A ordered vs next compute)

    {
      const long gbase = (long)u * 32 * 256;
#pragma unroll
      for (int p = 0; p < 2; ++p) {
        unsigned s = (unsigned)p * 512u + tid;
        unsigned row = s >> 5;
        unsigned seg = s & 31u;
        short8 vv = *(const short8*)&Ct[row * 256u + seg * 8u];
        *(short8*)(O + gbase + row * 256u + seg * 8u) = vv;
      }
    }
  }
#undef LOAD_A
#undef WRITE_A
}

// per edge: out = sigmoid( w2 . relu(U'[row] + V[col]) + b2 )
// 3-stage pipeline: idx(e+2) || rows(e+1) || compute(e)
#define EK_ITER 16
__global__ __launch_bounds__(256, 6) void k_edge(
    const unsigned short* __restrict__ U, const unsigned short* __restrict__ V,
    const int* __restrict__ eli, const float* __restrict__ w2,
    const float* __restrict__ b2, float* __restrict__ out) {
  const int tid = threadIdx.x;
  const int g = tid >> 4;
  const int j = tid & 15;
  float w2v[16];
#pragma unroll
  for (int q = 0; q < 8; ++q) {
    w2v[q] = w2[8 * j + q];
    w2v[8 + q] = w2[128 + 8 * j + q];
  }
  const float b2v = b2[0];
  const long base = (long)blockIdx.x * (16 * EK_ITER) + g;

#define CLAMP_E(k) \
  (((base + 16 * (k)) < E_TOT) ? (base + 16 * (k)) : (long)(E_TOT - 1))

  long eP = CLAMP_E(0);
  int rA = eli[eP], cA = eli[E_TOT + eP];
  long eQ = CLAMP_E(1);
  int rB = eli[eQ], cB = eli[E_TOT + eQ];
  short8 uA0 = *(const short8*)(U + (long)rA * 256 + 8 * j);
  short8 uA1 = *(const short8*)(U + (long)rA * 256 + 128 + 8 * j);
  short8 vA0 = *(const short8*)(V + (long)cA * 256 + 8 * j);
  short8 vA1 = *(const short8*)(V + (long)cA * 256 + 128 + 8 * j);
  short8 uB0, uB1, vB0, vB1;

#pragma unroll
  for (int it2 = 0; it2 < EK_ITER / 2; ++it2) {
    {
      long eN = CLAMP_E(2 * it2 + 2);
      int rN = eli[eN], cN = eli[E_TOT + eN];
      uB0 = *(const short8*)(U + (long)rB * 256 + 8 * j);
      uB1 = *(const short8*)(U + (long)rB * 256 + 128 + 8 * j);
      vB0 = *(const short8*)(V + (long)cB * 256 + 8 * j);
      vB1 = *(const short8*)(V + (long)cB * 256 + 128 + 8 * j);
      rB = rN; cB = cN;
      float p = 0.f;
#pragma unroll
      for (int q = 0; q < 8; ++q) {
        float a0 = bf2f((unsigned short)uA0[q]) + bf2f((unsigned short)vA0[q]);
        float a1 = bf2f((unsigned short)uA1[q]) + bf2f((unsigned short)vA1[q]);
        p = fmaf(fmaxf(a0, 0.f), w2v[q], p);
        p = fmaf(fmaxf(a1, 0.f), w2v[8 + q], p);
      }
      p += __shfl_xor(p, 1);
      p += __shfl_xor(p, 2);
      p += __shfl_xor(p, 4);
      p += __shfl_xor(p, 8);
      long e = base + 16 * (2 * it2);
      if (j == 0 && e < E_TOT) out[e] = 1.f / (1.f + __expf(-(p + b2v)));
    }
    {
      long eN = CLAMP_E(2 * it2 + 3);
      int rN = eli[eN], cN = eli[E_TOT + eN];
      uA0 = *(const short8*)(U + (long)rB * 256 + 8 * j);
      uA1 = *(const short8*)(U + (long)rB * 256 + 128 + 8 * j);
      vA0 = *(const short8*)(V + (long)cB * 256 + 8 * j);
      vA1 = *(const short8*)(V + (long)cB * 256 + 128 + 8 * j);
      rB = rN; cB = cN;
      float p = 0.f;
#pragma unroll
      for (int q = 0; q < 8; ++q) {
        float a0 = bf2f((unsigned short)uB0[q]) + bf2f((unsigned short)vB0[q]);
        float a1 = bf2f((unsigned short)uB1[q]) + bf2f((unsigned short)vB1[q]);
        p = fmaf(fmaxf(a0, 0.f), w2v[q], p);
        p = fmaf(fmaxf(a1, 0.f), w2v[8 + q], p);
      }
      p += __shfl_xor(p, 1);
      p += __shfl_xor(p, 2);
      p += __shfl_xor(p, 4);
      p += __shfl_xor(p, 8);
      long e = base + 16 * (2 * it2 + 1);
      if (j == 0 && e < E_TOT) out[e] = 1.f / (1.f + __expf(-(p + b2v)));
    }
  }
#undef CLAMP_E
}

extern "C" void kernel_launch(void* const* d_in, const int* in_sizes, int n_in,
                              void* d_out, int out_size, void* d_ws,
                              size_t ws_size, hipStream_t stream) {
  const float* zsrc = (const float*)d_in[0];
  const float* zdst = (const float*)d_in[1];
  const int* eli = (const int*)d_in[2];
  const float* w1 = (const float*)d_in[3];
  const float* b1 = (const float*)d_in[4];
  const float* w2 = (const float*)d_in[5];
  const float* b2 = (const float*)d_in[6];
  float* out = (float*)d_out;

  const size_t uv_bytes = (size_t)N_NODES * 256 * 2;  // 51.2 MB each
  unsigned short* U = (unsigned short*)d_ws;
  unsigned short* V = (unsigned short*)((char*)d_ws + uv_bytes);
  unsigned short* w1r2 = (unsigned short*)((char*)d_ws + 2 * uv_bytes);

  k_repack_w1h<<<512, 256, 0, stream>>>(w1, w1r2);
  k_node_gemm<<<256, 512, 0, stream>>>(zsrc, zdst, w1r2, b1, U, V);
  int nbe = (E_TOT + 16 * EK_ITER - 1) / (16 * EK_ITER);
  k_edge<<<nbe, 256, 0, stream>>>(U, V, eli, w2, b2, out);
}

// Round 12
// 149.020 us; speedup vs baseline: 1.7314x; 1.0416x over previous
//
#include <hip/hip_runtime.h>

#define E_TOT 500000
#define N_NODES 100000
#define NUNITS_H 3125   // 32-row units per half (3125*32 = 100000)

typedef __attribute__((ext_vector_type(16))) float f32x16;
typedef __attribute__((ext_vector_type(8))) short short8;
typedef __attribute__((ext_vector_type(4))) float f32x4;

__device__ __forceinline__ unsigned short f2bf(float f) {
  union { float f; unsigned u; } x; x.f = f;
  unsigned r = x.u + 0x7fffu + ((x.u >> 16) & 1u);
  return (unsigned short)(r >> 16);
}

__device__ __forceinline__ float bf2f(unsigned short s) {
  union { unsigned u; float f; } x; x.u = ((unsigned)s) << 16;
  return x.f;
}

// w1 (f32 [256][512]) -> w1r2 bf16 [half][kseg=0..31][n=0..255][j=0..7]
__global__ void k_repack_w1h(const float* __restrict__ w1,
                             unsigned short* __restrict__ w1r2) {
  int o = blockIdx.x * 256 + threadIdx.x;  // 131072 total
  int half = o >> 16;
  int kb = (o >> 11) & 31;
  int n = (o >> 3) & 255;
  int j = o & 7;
  w1r2[o] = f2bf(w1[n * 512 + half * 256 + kb * 8 + j]);
}

// U'[n] = zsrc[n] @ W1s^T + b1 (half 0) ; V[n] = zdst[n] @ W1d^T (half 1)
// v12: B panel in REGISTERS (64 VGPR/lane, loaded once, asm-pinned);
// A + C double-buffered in LDS -> ONE barrier per 32-row unit.
__global__ __launch_bounds__(512, 2) void k_node_gemm(
    const float* __restrict__ zsrc, const float* __restrict__ zdst,
    const unsigned short* __restrict__ w1r2, const float* __restrict__ b1,
    unsigned short* __restrict__ Uo, unsigned short* __restrict__ Vo) {
  __shared__ __align__(16) unsigned short Ap[2][8192];  // 2 x 16 KB
  __shared__ __align__(16) unsigned short Ct[2][8192];  // 2 x 16 KB

  const int half = blockIdx.x >> 7;   // 128 blocks per half
  const int bh = blockIdx.x & 127;
  const float* Z = half ? zdst : zsrc;
  unsigned short* O = half ? Vo : Uo;

  const unsigned tid = threadIdx.x;
  const unsigned l = tid & 63u;
  const unsigned wv = tid >> 6;     // wave 0..7 -> cols wv*32..wv*32+31
  const unsigned l31 = l & 31u;
  const unsigned hi = l >> 5;
  const unsigned arow = tid & 31u;  // A-staging row
  const unsigned ak2 = tid >> 5;    // A-staging 16-float granule (0..15)

  // ---- B fragments: 16 x short8 = 64 VGPRs, loaded once from L2 ----
  short8 brg[16];
  {
    const unsigned short* bb = w1r2 + (unsigned)half * 65536u;
#pragma unroll
    for (int k = 0; k < 16; ++k) {
      unsigned ks = (unsigned)k * 2u + hi;
      brg[k] = *(const short8*)(bb + (ks * 256u + wv * 32u + l31) * 8u);
      asm volatile("" : "+v"(brg[k]));  // opacity: cannot be re-materialized
    }
  }

  const float bi = half ? 0.f : b1[wv * 32u + l31];

  f32x4 ap[4];  // pending A: 16 floats = k [ak2*16, ak2*16+16)
#define LOAD_A(uu)                                                        \
  {                                                                       \
    const f32x4* p_ =                                                     \
        (const f32x4*)(Z + ((long)(uu)*32 + arow) * 256 + ak2 * 16u);     \
    ap[0] = p_[0]; ap[1] = p_[1]; ap[2] = p_[2]; ap[3] = p_[3];           \
  }
#define WRITE_A(bf_)                                                      \
  {                                                                       \
    _Pragma("unroll") for (int g = 0; g < 2; ++g) {                       \
      short8 sa;                                                          \
      sa[0] = (short)f2bf(ap[2*g].x);   sa[1] = (short)f2bf(ap[2*g].y);   \
      sa[2] = (short)f2bf(ap[2*g].z);   sa[3] = (short)f2bf(ap[2*g].w);   \
      sa[4] = (short)f2bf(ap[2*g+1].x); sa[5] = (short)f2bf(ap[2*g+1].y); \
      sa[6] = (short)f2bf(ap[2*g+1].z); sa[7] = (short)f2bf(ap[2*g+1].w); \
      *(short8*)&Ap[bf_][((2u*ak2 + (unsigned)g)*32u + arow)*8u] = sa;    \
    }                                                                     \
  }

  int u = bh;
  int cur = 0;
  LOAD_A(u);
  WRITE_A(0);
  __syncthreads();

  for (; u < NUNITS_H; u += 128) {
    int un = u + 128;
    if (un >= NUNITS_H) un = u;  // tail: reload same unit (harmless)
    LOAD_A(un);                  // lands during compute; consumed pre-barrier
    __builtin_amdgcn_sched_barrier(0);

    f32x16 acc = {0.f, 0.f, 0.f, 0.f, 0.f, 0.f, 0.f, 0.f,
                  0.f, 0.f, 0.f, 0.f, 0.f, 0.f, 0.f, 0.f};
#pragma unroll
    for (int kk = 0; kk < 16; ++kk) {
      unsigned ks = 2u * (unsigned)kk + hi;
      short8 af = *(const short8*)&Ap[cur][(ks * 32u + l31) * 8u];
      acc = __builtin_amdgcn_mfma_f32_32x32x16_bf16(af, brg[kk], acc, 0, 0, 0);
    }

    // C tile (this unit) + A (next unit) before the single barrier
#pragma unroll
    for (int r = 0; r < 16; ++r) {
      unsigned row32 = (unsigned)((r & 3) + 8 * (r >> 2)) + 4u * hi;
      Ct[cur][row32 * 256u + wv * 32u + l31] = f2bf(acc[r] + bi);
    }
    WRITE_A(cur ^ 1);
    __syncthreads();

    // full-line stores from Ct[cur] (fire-and-forget; drain overlaps next unit)
    {
      const long gbase = (long)u * 32 * 256;
#pragma unroll
      for (int p = 0; p < 2; ++p) {
        unsigned s = (unsigned)p * 512u + tid;
        unsigned row = s >> 5;
        unsigned seg = s & 31u;
        short8 vv = *(const short8*)&Ct[cur][row * 256u + seg * 8u];
        *(short8*)(O + gbase + row * 256u + seg * 8u) = vv;
      }
    }
    cur ^= 1;
  }
#undef LOAD_A
#undef WRITE_A
}

// per edge: out = sigmoid( w2 . relu(U'[row] + V[col]) + b2 )
// 3-stage pipeline: idx(e+2) || rows(e+1) || compute(e)
#define EK_ITER 16
__global__ __launch_bounds__(256, 6) void k_edge(
    const unsigned short* __restrict__ U, const unsigned short* __restrict__ V,
    const int* __restrict__ eli, const float* __restrict__ w2,
    const float* __restrict__ b2, float* __restrict__ out) {
  const int tid = threadIdx.x;
  const int g = tid >> 4;
  const int j = tid & 15;
  float w2v[16];
#pragma unroll
  for (int q = 0; q < 8; ++q) {
    w2v[q] = w2[8 * j + q];
    w2v[8 + q] = w2[128 + 8 * j + q];
  }
  const float b2v = b2[0];
  const long base = (long)blockIdx.x * (16 * EK_ITER) + g;

#define CLAMP_E(k) \
  (((base + 16 * (k)) < E_TOT) ? (base + 16 * (k)) : (long)(E_TOT - 1))

  long eP = CLAMP_E(0);
  int rA = eli[eP], cA = eli[E_TOT + eP];
  long eQ = CLAMP_E(1);
  int rB = eli[eQ], cB = eli[E_TOT + eQ];
  short8 uA0 = *(const short8*)(U + (long)rA * 256 + 8 * j);
  short8 uA1 = *(const short8*)(U + (long)rA * 256 + 128 + 8 * j);
  short8 vA0 = *(const short8*)(V + (long)cA * 256 + 8 * j);
  short8 vA1 = *(const short8*)(V + (long)cA * 256 + 128 + 8 * j);
  short8 uB0, uB1, vB0, vB1;

#pragma unroll
  for (int it2 = 0; it2 < EK_ITER / 2; ++it2) {
    {
      long eN = CLAMP_E(2 * it2 + 2);
      int rN = eli[eN], cN = eli[E_TOT + eN];
      uB0 = *(const short8*)(U + (long)rB * 256 + 8 * j);
      uB1 = *(const short8*)(U + (long)rB * 256 + 128 + 8 * j);
      vB0 = *(const short8*)(V + (long)cB * 256 + 8 * j);
      vB1 = *(const short8*)(V + (long)cB * 256 + 128 + 8 * j);
      rB = rN; cB = cN;
      float p = 0.f;
#pragma unroll
      for (int q = 0; q < 8; ++q) {
        float a0 = bf2f((unsigned short)uA0[q]) + bf2f((unsigned short)vA0[q]);
        float a1 = bf2f((unsigned short)uA1[q]) + bf2f((unsigned short)vA1[q]);
        p = fmaf(fmaxf(a0, 0.f), w2v[q], p);
        p = fmaf(fmaxf(a1, 0.f), w2v[8 + q], p);
      }
      p += __shfl_xor(p, 1);
      p += __shfl_xor(p, 2);
      p += __shfl_xor(p, 4);
      p += __shfl_xor(p, 8);
      long e = base + 16 * (2 * it2);
      if (j == 0 && e < E_TOT) out[e] = 1.f / (1.f + __expf(-(p + b2v)));
    }
    {
      long eN = CLAMP_E(2 * it2 + 3);
      int rN = eli[eN], cN = eli[E_TOT + eN];
      uA0 = *(const short8*)(U + (long)rB * 256 + 8 * j);
      uA1 = *(const short8*)(U + (long)rB * 256 + 128 + 8 * j);
      vA0 = *(const short8*)(V + (long)cB * 256 + 8 * j);
      vA1 = *(const short8*)(V + (long)cB * 256 + 128 + 8 * j);
      rB = rN; cB = cN;
      float p = 0.f;
#pragma unroll
      for (int q = 0; q < 8; ++q) {
        float a0 = bf2f((unsigned short)uB0[q]) + bf2f((unsigned short)vB0[q]);
        float a1 = bf2f((unsigned short)uB1[q]) + bf2f((unsigned short)vB1[q]);
        p = fmaf(fmaxf(a0, 0.f), w2v[q], p);
        p = fmaf(fmaxf(a1, 0.f), w2v[8 + q], p);
      }
      p += __shfl_xor(p, 1);
      p += __shfl_xor(p, 2);
      p += __shfl_xor(p, 4);
      p += __shfl_xor(p, 8);
      long e = base + 16 * (2 * it2 + 1);
      if (j == 0 && e < E_TOT) out[e] = 1.f / (1.f + __expf(-(p + b2v)));
    }
  }
#undef CLAMP_E
}

extern "C" void kernel_launch(void* const* d_in, const int* in_sizes, int n_in,
                              void* d_out, int out_size, void* d_ws,
                              size_t ws_size, hipStream_t stream) {
  const float* zsrc = (const float*)d_in[0];
  const float* zdst = (const float*)d_in[1];
  const int* eli = (const int*)d_in[2];
  const float* w1 = (const float*)d_in[3];
  const float* b1 = (const float*)d_in[4];
  const float* w2 = (const float*)d_in[5];
  const float* b2 = (const float*)d_in[6];
  float* out = (float*)d_out;

  const size_t uv_bytes = (size_t)N_NODES * 256 * 2;  // 51.2 MB each
  unsigned short* U = (unsigned short*)d_ws;
  unsigned short* V = (unsigned short*)((char*)d_ws + uv_bytes);
  unsigned short* w1r2 = (unsigned short*)((char*)d_ws + 2 * uv_bytes);

  k_repack_w1h<<<512, 256, 0, stream>>>(w1, w1r2);
  k_node_gemm<<<256, 512, 0, stream>>>(zsrc, zdst, w1r2, b1, U, V);
  int nbe = (E_TOT + 16 * EK_ITER - 1) / (16 * EK_ITER);
  k_edge<<<nbe, 256, 0, stream>>>(U, V, eli, w2, b2, out);
}

// Round 13
// 143.102 us; speedup vs baseline: 1.8030x; 1.0414x over previous
//
#include <hip/hip_runtime.h>

#define E_TOT 500000
#define N_NODES 100000
#define NUNITS_H 3125   // 32-row units per half (3125*32 = 100000)
#define SRD 128         // blocks per half (grid 256)

typedef __attribute__((ext_vector_type(16))) float f32x16;
typedef __attribute__((ext_vector_type(8))) short short8;
typedef __attribute__((ext_vector_type(4))) float f32x4;

__device__ __forceinline__ unsigned short f2bf(float f) {
  union { float f; unsigned u; } x; x.f = f;
  unsigned r = x.u + 0x7fffu + ((x.u >> 16) & 1u);
  return (unsigned short)(r >> 16);
}

__device__ __forceinline__ float bf2f(unsigned short s) {
  union { unsigned u; float f; } x; x.u = ((unsigned)s) << 16;
  return x.f;
}

// w1 (f32 [256][512]) -> w1r2 bf16 [half][kseg=0..31][n=0..255][j=0..7]
__global__ void k_repack_w1h(const float* __restrict__ w1,
                             unsigned short* __restrict__ w1r2) {
  int o = blockIdx.x * 256 + threadIdx.x;  // 131072 total
  int half = o >> 16;
  int kb = (o >> 11) & 31;
  int n = (o >> 3) & 255;
  int j = o & 7;
  w1r2[o] = f2bf(w1[n * 512 + half * 256 + kb * 8 + j]);
}

// U'[n] = zsrc[n] @ W1s^T + b1 (half 0) ; V[n] = zdst[n] @ W1d^T (half 1)
// v13: v12 + depth-3 A prefetch (3 x 32KB units in flight per block) so the
// per-CU HBM pipe never goes idle. B frags live in AGPRs; 1 barrier/unit.
__global__ __launch_bounds__(512, 1) void k_node_gemm(
    const float* __restrict__ zsrc, const float* __restrict__ zdst,
    const unsigned short* __restrict__ w1r2, const float* __restrict__ b1,
    unsigned short* __restrict__ Uo, unsigned short* __restrict__ Vo) {
  __shared__ __align__(16) unsigned short Ap[2][8192];  // 2 x 16 KB
  __shared__ __align__(16) unsigned short Ct[2][8192];  // 2 x 16 KB

  const int half = blockIdx.x >> 7;   // 128 blocks per half
  const int bh = blockIdx.x & 127;
  const float* Z = half ? zdst : zsrc;
  unsigned short* O = half ? Vo : Uo;

  const unsigned tid = threadIdx.x;
  const unsigned l = tid & 63u;
  const unsigned wv = tid >> 6;     // wave 0..7 -> cols wv*32..wv*32+31
  const unsigned l31 = l & 31u;
  const unsigned hi = l >> 5;
  const unsigned arow = tid & 31u;  // A-staging row
  const unsigned ak2 = tid >> 5;    // A-staging 16-float granule (0..15)

  // ---- B fragments: 16 x short8, loaded once (compiler parks in AGPRs) ----
  short8 brg[16];
  {
    const unsigned short* bb = w1r2 + (unsigned)half * 65536u;
#pragma unroll
    for (int k = 0; k < 16; ++k) {
      unsigned ks = (unsigned)k * 2u + hi;
      brg[k] = *(const short8*)(bb + (ks * 256u + wv * 32u + l31) * 8u);
      asm volatile("" : "+v"(brg[k]));  // opacity: no re-materialization
    }
  }

  const float bi = half ? 0.f : b1[wv * 32u + l31];

  f32x4 apA[4], apB[4], apC[4];  // 3 pending A units (16 regs each)

#define LOAD_A(uu, ap_)                                                   \
  {                                                                       \
    int uc_ = (uu); if (uc_ >= NUNITS_H) uc_ = NUNITS_H - 1;              \
    const f32x4* p_ =                                                     \
        (const f32x4*)(Z + ((long)uc_ * 32 + arow) * 256 + ak2 * 16u);    \
    ap_[0] = p_[0]; ap_[1] = p_[1]; ap_[2] = p_[2]; ap_[3] = p_[3];       \
  }
#define WRITE_A(ap_, bf_)                                                 \
  {                                                                       \
    _Pragma("unroll") for (int g = 0; g < 2; ++g) {                       \
      short8 sa;                                                          \
      sa[0] = (short)f2bf(ap_[2*g].x);   sa[1] = (short)f2bf(ap_[2*g].y); \
      sa[2] = (short)f2bf(ap_[2*g].z);   sa[3] = (short)f2bf(ap_[2*g].w); \
      sa[4] = (short)f2bf(ap_[2*g+1].x); sa[5] = (short)f2bf(ap_[2*g+1].y); \
      sa[6] = (short)f2bf(ap_[2*g+1].z); sa[7] = (short)f2bf(ap_[2*g+1].w); \
      *(short8*)&Ap[bf_][((2u*ak2 + (unsigned)g)*32u + arow)*8u] = sa;    \
    }                                                                     \
  }

// one unit: issue A(u+3S) into NEW, compute Ap[cur], stage WR (=A(u+S)),
// single barrier, full-line stores.
#define BODY(uu, NEW, WR)                                                 \
  {                                                                       \
    LOAD_A((uu) + 3 * SRD, NEW);                                          \
    __builtin_amdgcn_sched_barrier(0);                                    \
    f32x16 acc = {0.f, 0.f, 0.f, 0.f, 0.f, 0.f, 0.f, 0.f,                 \
                  0.f, 0.f, 0.f, 0.f, 0.f, 0.f, 0.f, 0.f};                \
    _Pragma("unroll") for (int kk = 0; kk < 16; ++kk) {                   \
      unsigned ks = 2u * (unsigned)kk + hi;                               \
      short8 af = *(const short8*)&Ap[cur][(ks * 32u + l31) * 8u];        \
      acc = __builtin_amdgcn_mfma_f32_32x32x16_bf16(af, brg[kk], acc, 0, 0, 0); \
    }                                                                     \
    _Pragma("unroll") for (int r = 0; r < 16; ++r) {                      \
      unsigned row32 = (unsigned)((r & 3) + 8 * (r >> 2)) + 4u * hi;      \
      Ct[cur][row32 * 256u + wv * 32u + l31] = f2bf(acc[r] + bi);         \
    }                                                                     \
    WRITE_A(WR, cur ^ 1);                                                 \
    __syncthreads();                                                      \
    {                                                                     \
      const long gbase = (long)(uu) * 32 * 256;                           \
      _Pragma("unroll") for (int p = 0; p < 2; ++p) {                     \
        unsigned s = (unsigned)p * 512u + tid;                            \
        unsigned row = s >> 5;                                            \
        unsigned seg = s & 31u;                                           \
        short8 vv = *(const short8*)&Ct[cur][row * 256u + seg * 8u];      \
        *(short8*)(O + gbase + row * 256u + seg * 8u) = vv;               \
      }                                                                   \
    }                                                                     \
    cur ^= 1;                                                             \
  }

  int u = bh;
  int cur = 0;
  // prologue: A(u) -> LDS now; A(u+S), A(u+2S) in flight
  LOAD_A(u, apA);
  WRITE_A(apA, 0);
  LOAD_A(u + SRD, apB);
  LOAD_A(u + 2 * SRD, apC);
  __syncthreads();

  // rotation: (NEW,WR) = (A,B), (B,C), (C,A)
  for (; u < NUNITS_H;) {
    BODY(u, apA, apB);
    u += SRD;
    if (u >= NUNITS_H) break;
    BODY(u, apB, apC);
    u += SRD;
    if (u >= NUNITS_H) break;
    BODY(u, apC, apA);
    u += SRD;
  }
#undef BODY
#undef LOAD_A
#undef WRITE_A
}

// per edge: out = sigmoid( w2 . relu(U'[row] + V[col]) + b2 )
// 3-stage pipeline: idx(e+2) || rows(e+1) || compute(e)
#define EK_ITER 16
__global__ __launch_bounds__(256, 6) void k_edge(
    const unsigned short* __restrict__ U, const unsigned short* __restrict__ V,
    const int* __restrict__ eli, const float* __restrict__ w2,
    const float* __restrict__ b2, float* __restrict__ out) {
  const int tid = threadIdx.x;
  const int g = tid >> 4;
  const int j = tid & 15;
  float w2v[16];
#pragma unroll
  for (int q = 0; q < 8; ++q) {
    w2v[q] = w2[8 * j + q];
    w2v[8 + q] = w2[128 + 8 * j + q];
  }
  const float b2v = b2[0];
  const long base = (long)blockIdx.x * (16 * EK_ITER) + g;

#define CLAMP_E(k) \
  (((base + 16 * (k)) < E_TOT) ? (base + 16 * (k)) : (long)(E_TOT - 1))

  long eP = CLAMP_E(0);
  int rA = eli[eP], cA = eli[E_TOT + eP];
  long eQ = CLAMP_E(1);
  int rB = eli[eQ], cB = eli[E_TOT + eQ];
  short8 uA0 = *(const short8*)(U + (long)rA * 256 + 8 * j);
  short8 uA1 = *(const short8*)(U + (long)rA * 256 + 128 + 8 * j);
  short8 vA0 = *(const short8*)(V + (long)cA * 256 + 8 * j);
  short8 vA1 = *(const short8*)(V + (long)cA * 256 + 128 + 8 * j);
  short8 uB0, uB1, vB0, vB1;

#pragma unroll
  for (int it2 = 0; it2 < EK_ITER / 2; ++it2) {
    {
      long eN = CLAMP_E(2 * it2 + 2);
      int rN = eli[eN], cN = eli[E_TOT + eN];
      uB0 = *(const short8*)(U + (long)rB * 256 + 8 * j);
      uB1 = *(const short8*)(U + (long)rB * 256 + 128 + 8 * j);
      vB0 = *(const short8*)(V + (long)cB * 256 + 8 * j);
      vB1 = *(const short8*)(V + (long)cB * 256 + 128 + 8 * j);
      rB = rN; cB = cN;
      float p = 0.f;
#pragma unroll
      for (int q = 0; q < 8; ++q) {
        float a0 = bf2f((unsigned short)uA0[q]) + bf2f((unsigned short)vA0[q]);
        float a1 = bf2f((unsigned short)uA1[q]) + bf2f((unsigned short)vA1[q]);
        p = fmaf(fmaxf(a0, 0.f), w2v[q], p);
        p = fmaf(fmaxf(a1, 0.f), w2v[8 + q], p);
      }
      p += __shfl_xor(p, 1);
      p += __shfl_xor(p, 2);
      p += __shfl_xor(p, 4);
      p += __shfl_xor(p, 8);
      long e = base + 16 * (2 * it2);
      if (j == 0 && e < E_TOT) out[e] = 1.f / (1.f + __expf(-(p + b2v)));
    }
    {
      long eN = CLAMP_E(2 * it2 + 3);
      int rN = eli[eN], cN = eli[E_TOT + eN];
      uA0 = *(const short8*)(U + (long)rB * 256 + 8 * j);
      uA1 = *(const short8*)(U + (long)rB * 256 + 128 + 8 * j);
      vA0 = *(const short8*)(V + (long)cB * 256 + 8 * j);
      vA1 = *(const short8*)(V + (long)cB * 256 + 128 + 8 * j);
      rB = rN; cB = cN;
      float p = 0.f;
#pragma unroll
      for (int q = 0; q < 8; ++q) {
        float a0 = bf2f((unsigned short)uB0[q]) + bf2f((unsigned short)vB0[q]);
        float a1 = bf2f((unsigned short)uB1[q]) + bf2f((unsigned short)vB1[q]);
        p = fmaf(fmaxf(a0, 0.f), w2v[q], p);
        p = fmaf(fmaxf(a1, 0.f), w2v[8 + q], p);
      }
      p += __shfl_xor(p, 1);
      p += __shfl_xor(p, 2);
      p += __shfl_xor(p, 4);
      p += __shfl_xor(p, 8);
      long e = base + 16 * (2 * it2 + 1);
      if (j == 0 && e < E_TOT) out[e] = 1.f / (1.f + __expf(-(p + b2v)));
    }
  }
#undef CLAMP_E
}

extern "C" void kernel_launch(void* const* d_in, const int* in_sizes, int n_in,
                              void* d_out, int out_size, void* d_ws,
                              size_t ws_size, hipStream_t stream) {
  const float* zsrc = (const float*)d_in[0];
  const float* zdst = (const float*)d_in[1];
  const int* eli = (const int*)d_in[2];
  const float* w1 = (const float*)d_in[3];
  const float* b1 = (const float*)d_in[4];
  const float* w2 = (const float*)d_in[5];
  const float* b2 = (const float*)d_in[6];
  float* out = (float*)d_out;

  const size_t uv_bytes = (size_t)N_NODES * 256 * 2;  // 51.2 MB each
  unsigned short* U = (unsigned short*)d_ws;
  unsigned short* V = (unsigned short*)((char*)d_ws + uv_bytes);
  unsigned short* w1r2 = (unsigned short*)((char*)d_ws + 2 * uv_bytes);

  k_repack_w1h<<<512, 256, 0, stream>>>(w1, w1r2);
  k_node_gemm<<<256, 512, 0, stream>>>(zsrc, zdst, w1r2, b1, U, V);
  int nbe = (E_TOT + 16 * EK_ITER - 1) / (16 * EK_ITER);
  k_edge<<<nbe, 256, 0, stream>>>(U, V, eli, w2, b2, out);
}